// Round 8
// baseline (327.760 us; speedup 1.0000x reference)
//
#include <hip/hip_runtime.h>
#include <cstdint>

// BasisFunction1D: out[o,b] = sum_i (1-d)*P[idx,o,i] + d*P[idx+1,o,i]
//
// R14 = R13 resubmitted verbatim (R7 bench round failed on infra:
// "MI355X container failed twice" -- no compile error, no timing).
//
// R13: counted-vmcnt pipelined main_k (T3+T4 schedule from the CDNA4 guide).
//   Invariant 38-48us across R6/R8/R10/R12 despite occupancy/staging changes
//   => the per-phase __syncthreads() vmcnt(0) drain is the cost (m233).
//   R13 main loop: 3-slab ring (3x16KB), per phase:
//     issue T(p+1) [8 coalesced dwords] -> issue gll(p+2) [16B/thread]
//     -> 8 gathers+fdot2 -> s_waitcnt vmcnt(1) lgkmcnt(0) -> raw s_barrier
//     -> sched_barrier(0).
//   gll(p+2) stays IN FLIGHT across the barrier (vmcnt never 0 until tail).
//   lgkmcnt(0) at the barrier covers the slab WAR hazard (ring-3: a slab is
//   rewritten one barrier after its readers finish).
//   T kept as coalesced T[i][b] (R12's T2[b][i] cost ~13us scattered VMEM).
//   Full 128 i per block, direct NT out, no partials/reduce.

#define NG 128
#define NI 128
#define NO 128
#define NB 8192
#define PH 8
#define NPH 16

using half2v = __attribute__((ext_vector_type(2))) _Float16;

__device__ inline uint32_t pack_f16x2(float lo, float hi) {
    _Float16 hl = (_Float16)lo, hh = (_Float16)hi;
    return (uint32_t)__builtin_bit_cast(unsigned short, hl) |
           ((uint32_t)__builtin_bit_cast(unsigned short, hh) << 16);
}

__device__ inline void load_lds16(const uint32_t* g, uint32_t* l) {
    __builtin_amdgcn_global_load_lds(
        (const __attribute__((address_space(1))) uint32_t*)g,
        (__attribute__((address_space(3))) uint32_t*)l, 16, 0, 0);
}

// ---- K1: P[g,o,i] -> Q2[((s*NI+i)*NG+g)*4+ow] = pack(P, dP), o=s*4+ow ----
// (proven R10 version: 64B-contiguous stores)
__global__ __launch_bounds__(256) void build_q(const float* __restrict__ P,
                                               uint32_t* __restrict__ Q2) {
    __shared__ float L[5][16][128];             // 40 KB
    const int gb = blockIdx.x >> 3;
    const int ob = blockIdx.x & 7;
    const int g0 = gb * 4;
    const int o0 = ob * 16;
    const int s0 = ob * 4;
    const int t  = threadIdx.x;
    #pragma unroll
    for (int pass = 0; pass < 40; ++pass) {     // 80 rows x 128 i
        int row = pass * 2 + (t >> 7);
        int i   = t & 127;
        int gg  = row >> 4, ol = row & 15;
        L[gg][ol][i] = P[(size_t)(g0 + gg) * (NO * NI) + (o0 + ol) * NI + i];
    }
    __syncthreads();
    #pragma unroll
    for (int pp = 0; pp < 2; ++pp) {
        int item = pp * 256 + t;                // 4 sl x 128 i
        int i  = item & 127;
        int sl = item >> 7;
        uint32_t* dst = Q2 + ((size_t)((s0 + sl) * NI + i) * NG + g0) * 4;
        #pragma unroll
        for (int gg = 0; gg < 4; ++gg) {
            uint32_t r[4];
            #pragma unroll
            for (int ow = 0; ow < 4; ++ow) {
                float pl = L[gg][sl * 4 + ow][i];
                float dd = L[gg + 1][sl * 4 + ow][i] - pl;
                r[ow] = pack_f16x2(pl, dd);
            }
            *(uint4*)(dst + gg * 4) = make_uint4(r[0], r[1], r[2], r[3]);
        }
    }
}

// ---- K2: bucketize x -> T[i][b] = (idx*16) | (f16(d) << 16) (coalesced) --
__global__ __launch_bounds__(256) void build_t(const float* __restrict__ x,
                                               const float* __restrict__ borders,
                                               const float* __restrict__ icl,
                                               uint32_t* __restrict__ T) {
    const int e0 = (blockIdx.x * 256 + threadIdx.x) * 4;
    const float4 xv = *(const float4*)(x + e0);
    uint32_t r[4];
    const float xs[4] = {xv.x, xv.y, xv.z, xv.w};
    #pragma unroll
    for (int k = 0; k < 4; ++k) {
        float v = xs[k];
        float ea = __expf(-fabsf(v));
        float cdf = v > 0.f ? 1.f - 0.5f * ea : 0.5f * ea;
        int idx = (int)(cdf * 128.f);
        idx = idx > 127 ? 127 : idx;
        float d = (v - borders[idx]) * icl[idx];
        _Float16 hd = (_Float16)d;
        r[k] = ((uint32_t)idx << 4) |
               ((uint32_t)__builtin_bit_cast(unsigned short, hd) << 16);
    }
    *(uint4*)(T + e0) = make_uint4(r[0], r[1], r[2], r[3]);
}

// ---- K3: main. 1024 thr; 1024 b x 4 o x 128 i; ring-3 counted-vmcnt ------
__global__ __launch_bounds__(1024) void main_k(const uint32_t* __restrict__ Q2,
                                               const uint32_t* __restrict__ T,
                                               float* __restrict__ out) {
    __shared__ __align__(16) uint32_t slab[3][PH * NG * 4];   // 3 x 16 KB
    const int t   = threadIdx.x;
    const int bx  = blockIdx.x;
    const int s   = bx & 31;                    // o-slice; 8 bt-blocks share
    const int bt  = bx >> 5;                    //   one s-slab on one XCD
    const int bme = (bt << 10) | t;
    const uint32_t* Qs = Q2 + (size_t)s * (NI * NG * 4);

    float a0 = 0.f, a1 = 0.f, a2 = 0.f, a3 = 0.f;

    uint32_t tc[PH];
    // prologue: T(0), then gll(0), gll(1); drain all but gll(1)
    #pragma unroll
    for (int il = 0; il < PH; ++il)
        tc[il] = T[(size_t)il * NB + bme];
    asm volatile("" ::: "memory");              // order: T(0) before glls
    load_lds16(Qs + (size_t)t * 4,                  &slab[0][t * 4]);
    load_lds16(Qs + (size_t)(PH * NG * 4) + t * 4,  &slab[1][t * 4]);
    asm volatile("s_waitcnt vmcnt(1)" ::: "memory");
    __builtin_amdgcn_s_barrier();
    __builtin_amdgcn_sched_barrier(0);

    #pragma unroll
    for (int p = 0; p < NPH; ++p) {
        uint32_t tn[PH];
        if (p < NPH - 1) {                      // T(p+1): coalesced dwords
            #pragma unroll
            for (int il = 0; il < PH; ++il)
                tn[il] = T[(size_t)((p + 1) * PH + il) * NB + bme];
        }
        asm volatile("" ::: "memory");          // order: T before gll
        if (p < NPH - 2) {                      // gll(p+2) -> ring slot
            load_lds16(Qs + (size_t)(p + 2) * (PH * NG * 4) + t * 4,
                       &slab[(p + 2) % 3][t * 4]);
        }
        const char* sp = (const char*)&slab[p % 3][0];
        #pragma unroll
        for (int il = 0; il < PH; ++il) {
            uint32_t tw  = tc[il];
            uint32_t off = tw & 0xFFFFu;                    // idx*16 bytes
            uint32_t w2b = (tw & 0xFFFF0000u) | 0x3C00u;    // {1.0h, d}
            uint4 q = *(const uint4*)(sp + il * 2048 + off);
            half2v w2 = __builtin_bit_cast(half2v, w2b);
            a0 = __builtin_amdgcn_fdot2(__builtin_bit_cast(half2v, q.x), w2, a0, false);
            a1 = __builtin_amdgcn_fdot2(__builtin_bit_cast(half2v, q.y), w2, a1, false);
            a2 = __builtin_amdgcn_fdot2(__builtin_bit_cast(half2v, q.z), w2, a2, false);
            a3 = __builtin_amdgcn_fdot2(__builtin_bit_cast(half2v, q.w), w2, a3, false);
        }
        if (p < NPH - 1) {
            #pragma unroll
            for (int il = 0; il < PH; ++il)
                tc[il] = tn[il];
            // counted wait: keep gll(p+2) in flight across the barrier.
            // lgkmcnt(0): this wave's slab reads complete before the slot
            // is rewritten one barrier later (ring-3 WAR).
            if (p < NPH - 2)
                asm volatile("s_waitcnt vmcnt(1) lgkmcnt(0)" ::: "memory");
            else
                asm volatile("s_waitcnt vmcnt(0) lgkmcnt(0)" ::: "memory");
            __builtin_amdgcn_s_barrier();
            __builtin_amdgcn_sched_barrier(0);
        }
    }

    // epilogue: o = s*4 + {0..3}; 1024-lane contiguous runs per o
    size_t ob = (size_t)(s * 4) * NB + bme;
    __builtin_nontemporal_store(a0, out + ob);
    __builtin_nontemporal_store(a1, out + ob + NB);
    __builtin_nontemporal_store(a2, out + ob + 2 * (size_t)NB);
    __builtin_nontemporal_store(a3, out + ob + 3 * (size_t)NB);
}

extern "C" void kernel_launch(void* const* d_in, const int* in_sizes, int n_in,
                              void* d_out, int out_size, void* d_ws, size_t ws_size,
                              hipStream_t stream) {
    const float* x       = (const float*)d_in[0];
    const float* P       = (const float*)d_in[1];
    const float* borders = (const float*)d_in[2];
    const float* icl     = (const float*)d_in[3];
    float* out = (float*)d_out;

    uint32_t* Q2 = (uint32_t*)d_ws;                 // 8 MB
    uint32_t* T  = Q2 + (size_t)NO * NI * NG;       // 4 MB

    hipLaunchKernelGGL(build_q, dim3(256), dim3(256), 0, stream, P, Q2);
    hipLaunchKernelGGL(build_t, dim3(NI * NB / 1024), dim3(256), 0, stream,
                       x, borders, icl, T);
    hipLaunchKernelGGL(main_k, dim3(256), dim3(1024), 0, stream, Q2, T, out);
}

// Round 9
// 108.623 us; speedup vs baseline: 3.0174x; 3.0174x over previous
//
#include <hip/hip_runtime.h>
#include <cstdint>

// BasisFunction1D: out[o,b] = sum_i (1-d)*P[idx,o,i] + d*P[idx+1,o,i]
//
// R15: persistent-slab ZERO-BARRIER main_k.
//   R13/R14 post-mortem: counted-vmcnt + sched_barrier pins at 64 VGPR ->
//   ~500MB scratch spill churn, 265us. Scheduling-level fixes are dead.
//   Structural fix instead: the per-(s, i-half) Q panel is 64i x 128g x 4o
//   x 4B = exactly 128 KB -> LDS-resident WHOLE. Stage once (gll w16, one
//   __syncthreads), then the main loop has NO barriers, NO restaging, NO
//   vmcnt drains: waves free-run over 2048 b x 64 i gathers, T prefetched
//   16-deep per chunk (coalesced stride-NB dwords).
//   Grid 256 = 32 s x (2 ih x 4 bq); bx&7 = ih*4+bq so the 32 blocks
//   sharing one 512KB T-window live on one XCD (T demand -> L2 hits).
//   i-half partials + proven reduce_k (4KB-contiguous runs, no RMW).

#define NG 128
#define NI 128
#define NO 128
#define NB 8192

using half2v  = __attribute__((ext_vector_type(2))) _Float16;
using float4v = __attribute__((ext_vector_type(4))) float;

__device__ inline uint32_t pack_f16x2(float lo, float hi) {
    _Float16 hl = (_Float16)lo, hh = (_Float16)hi;
    return (uint32_t)__builtin_bit_cast(unsigned short, hl) |
           ((uint32_t)__builtin_bit_cast(unsigned short, hh) << 16);
}

__device__ inline void load_lds16(const uint32_t* g, uint32_t* l) {
    __builtin_amdgcn_global_load_lds(
        (const __attribute__((address_space(1))) uint32_t*)g,
        (__attribute__((address_space(3))) uint32_t*)l, 16, 0, 0);
}

// ---- K1: P[g,o,i] -> Q2[((s*NI+i)*NG+g)*4+ow] = pack(P, dP), o=s*4+ow ----
// (proven R10 version: 64B-contiguous stores)
__global__ __launch_bounds__(256) void build_q(const float* __restrict__ P,
                                               uint32_t* __restrict__ Q2) {
    __shared__ float L[5][16][128];             // 40 KB
    const int gb = blockIdx.x >> 3;
    const int ob = blockIdx.x & 7;
    const int g0 = gb * 4;
    const int o0 = ob * 16;
    const int s0 = ob * 4;
    const int t  = threadIdx.x;
    #pragma unroll
    for (int pass = 0; pass < 40; ++pass) {     // 80 rows x 128 i
        int row = pass * 2 + (t >> 7);
        int i   = t & 127;
        int gg  = row >> 4, ol = row & 15;
        L[gg][ol][i] = P[(size_t)(g0 + gg) * (NO * NI) + (o0 + ol) * NI + i];
    }
    __syncthreads();
    #pragma unroll
    for (int pp = 0; pp < 2; ++pp) {
        int item = pp * 256 + t;                // 4 sl x 128 i
        int i  = item & 127;
        int sl = item >> 7;
        uint32_t* dst = Q2 + ((size_t)((s0 + sl) * NI + i) * NG + g0) * 4;
        #pragma unroll
        for (int gg = 0; gg < 4; ++gg) {
            uint32_t r[4];
            #pragma unroll
            for (int ow = 0; ow < 4; ++ow) {
                float pl = L[gg][sl * 4 + ow][i];
                float dd = L[gg + 1][sl * 4 + ow][i] - pl;
                r[ow] = pack_f16x2(pl, dd);
            }
            *(uint4*)(dst + gg * 4) = make_uint4(r[0], r[1], r[2], r[3]);
        }
    }
}

// ---- K2: bucketize x -> T[i][b] = (idx*16) | (f16(d) << 16) (coalesced) --
__global__ __launch_bounds__(256) void build_t(const float* __restrict__ x,
                                               const float* __restrict__ borders,
                                               const float* __restrict__ icl,
                                               uint32_t* __restrict__ T) {
    const int e0 = (blockIdx.x * 256 + threadIdx.x) * 4;
    const float4 xv = *(const float4*)(x + e0);
    uint32_t r[4];
    const float xs[4] = {xv.x, xv.y, xv.z, xv.w};
    #pragma unroll
    for (int k = 0; k < 4; ++k) {
        float v = xs[k];
        float ea = __expf(-fabsf(v));
        float cdf = v > 0.f ? 1.f - 0.5f * ea : 0.5f * ea;
        int idx = (int)(cdf * 128.f);
        idx = idx > 127 ? 127 : idx;
        float d = (v - borders[idx]) * icl[idx];
        _Float16 hd = (_Float16)d;
        r[k] = ((uint32_t)idx << 4) |
               ((uint32_t)__builtin_bit_cast(unsigned short, hd) << 16);
    }
    *(uint4*)(T + e0) = make_uint4(r[0], r[1], r[2], r[3]);
}

// ---- K3: main. 1024 thr; persistent 128KB slab; 2048 b x 4 o x 64 i ------
// No barriers in the main loop: slab is read-only after the one-time stage.
__global__ __launch_bounds__(1024, 4) void main_k(const uint32_t* __restrict__ Q2,
                                                  const uint32_t* __restrict__ T,
                                                  float* __restrict__ part) {
    __shared__ __align__(16) uint32_t slab[64 * NG * 4];   // 128 KB
    const int t   = threadIdx.x;
    const int bx  = blockIdx.x;
    const int win = bx & 7;                     // ih*4+bq -> XCD affinity
    const int s   = bx >> 3;                    // o-slice (4 o), 0..31
    const int ih  = win >> 2;                   // i-half
    const int bq  = win & 3;                    // b-quarter (2048 b)
    const uint32_t* Qs = Q2 + ((size_t)s * NI + ih * 64) * (NG * 4);

    // one-time stage: whole 64i x 128g x 4o panel -> LDS (8 x gll16/thread)
    #pragma unroll
    for (int k = 0; k < 8; ++k)
        load_lds16(Qs + (size_t)(t + k * 1024) * 4, &slab[(t + k * 1024) * 4]);
    __syncthreads();                            // ONLY barrier in the kernel

    #pragma unroll
    for (int bb = 0; bb < 2; ++bb) {
        const int bcol = (bq << 11) + (bb << 10) + t;
        const uint32_t* Tb = T + (size_t)(ih * 64) * NB + bcol;
        float a0 = 0.f, a1 = 0.f, a2 = 0.f, a3 = 0.f;
        uint32_t tt[16];
        #pragma unroll
        for (int il = 0; il < 16; ++il)
            tt[il] = Tb[(size_t)il * NB];
        #pragma unroll
        for (int ic = 0; ic < 4; ++ic) {
            uint32_t tn[16];
            if (ic < 3) {                       // prefetch next 16-i chunk
                #pragma unroll
                for (int il = 0; il < 16; ++il)
                    tn[il] = Tb[(size_t)((ic + 1) * 16 + il) * NB];
            }
            const char* sp = (const char*)slab + ic * 32768;
            #pragma unroll
            for (int il = 0; il < 16; ++il) {
                uint32_t tw  = tt[il];
                uint32_t off = tw & 0xFFFFu;                 // idx*16 bytes
                uint32_t w2b = (tw & 0xFFFF0000u) | 0x3C00u; // {1.0h, d}
                uint4 q = *(const uint4*)(sp + il * 2048 + off);
                half2v w2 = __builtin_bit_cast(half2v, w2b);
                a0 = __builtin_amdgcn_fdot2(__builtin_bit_cast(half2v, q.x), w2, a0, false);
                a1 = __builtin_amdgcn_fdot2(__builtin_bit_cast(half2v, q.y), w2, a1, false);
                a2 = __builtin_amdgcn_fdot2(__builtin_bit_cast(half2v, q.z), w2, a2, false);
                a3 = __builtin_amdgcn_fdot2(__builtin_bit_cast(half2v, q.w), w2, a3, false);
            }
            if (ic < 3) {
                #pragma unroll
                for (int il = 0; il < 16; ++il)
                    tt[il] = tn[il];
            }
        }
        // part[ih][o][b]: 4KB-contiguous run per o across the block
        float* po = part + (size_t)ih * (NO * NB) + (size_t)(s * 4) * NB + bcol;
        po[0]              = a0;
        po[NB]             = a1;
        po[2 * (size_t)NB] = a2;
        po[3 * (size_t)NB] = a3;
    }
}

// ---- K4: out = part0 + part1 (1M floats) ----
__global__ __launch_bounds__(256) void reduce_k(const float* __restrict__ part,
                                                float* __restrict__ out) {
    const int e0 = (blockIdx.x * 256 + threadIdx.x) * 4;
    const float4v v0 = *(const float4v*)(part + e0);
    const float4v v1 = *(const float4v*)(part + (size_t)NO * NB + e0);
    const float4v r  = v0 + v1;
    __builtin_nontemporal_store(r, (float4v*)(out + e0));
}

extern "C" void kernel_launch(void* const* d_in, const int* in_sizes, int n_in,
                              void* d_out, int out_size, void* d_ws, size_t ws_size,
                              hipStream_t stream) {
    const float* x       = (const float*)d_in[0];
    const float* P       = (const float*)d_in[1];
    const float* borders = (const float*)d_in[2];
    const float* icl     = (const float*)d_in[3];
    float* out = (float*)d_out;

    uint32_t* Q2  = (uint32_t*)d_ws;                 // 8 MB
    uint32_t* T   = Q2 + (size_t)NO * NI * NG;       // 4 MB
    float*    prt = (float*)(T + (size_t)NI * NB);   // 8 MB (two halves)

    hipLaunchKernelGGL(build_q, dim3(256), dim3(256), 0, stream, P, Q2);
    hipLaunchKernelGGL(build_t, dim3(NI * NB / 1024), dim3(256), 0, stream,
                       x, borders, icl, T);
    hipLaunchKernelGGL(main_k, dim3(256), dim3(1024), 0, stream, Q2, T, prt);
    hipLaunchKernelGGL(reduce_k, dim3(NO * NB / 1024), dim3(256), 0, stream,
                       prt, out);
}

// Round 10
// 104.978 us; speedup vs baseline: 3.1222x; 1.0347x over previous
//
#include <hip/hip_runtime.h>
#include <cstdint>

// BasisFunction1D: out[o,b] = sum_i (1-d)*P[idx,o,i] + d*P[idx+1,o,i]
//
// R16 = R15 (zero-barrier persistent slab, clean traffic) x R10 (32 waves/CU).
//   R15 post-mortem: 128KB slab -> 1 block/CU -> 16 waves -> warm ~53us.
//   16-wave configs: 41-53us; 32-wave: 38-48us. Occupancy IS a lever.
//   R16: 64KB slab (32i x 128g x 4o) -> 2 blocks/CU = 32 waves, and the
//   main loop still has ZERO barriers (slab read-only after one stage).
//   4-way i-split partials (contiguous 4KB runs, proven cheap) + reduce.
//   Grid 1024 = (xcd=bt) x 32 s x 4 iq: each XCD holds 4 T-windows
//   (512KB, L2) and streams its Q slabs once (64MB total fetch).

#define NG 128
#define NI 128
#define NO 128
#define NB 8192

using half2v  = __attribute__((ext_vector_type(2))) _Float16;
using float4v = __attribute__((ext_vector_type(4))) float;

__device__ inline uint32_t pack_f16x2(float lo, float hi) {
    _Float16 hl = (_Float16)lo, hh = (_Float16)hi;
    return (uint32_t)__builtin_bit_cast(unsigned short, hl) |
           ((uint32_t)__builtin_bit_cast(unsigned short, hh) << 16);
}

__device__ inline void load_lds16(const uint32_t* g, uint32_t* l) {
    __builtin_amdgcn_global_load_lds(
        (const __attribute__((address_space(1))) uint32_t*)g,
        (__attribute__((address_space(3))) uint32_t*)l, 16, 0, 0);
}

// ---- K1: P[g,o,i] -> Q2[((s*NI+i)*NG+g)*4+ow] = pack(P, dP), o=s*4+ow ----
// (proven R10 version: 64B-contiguous stores)
__global__ __launch_bounds__(256) void build_q(const float* __restrict__ P,
                                               uint32_t* __restrict__ Q2) {
    __shared__ float L[5][16][128];             // 40 KB
    const int gb = blockIdx.x >> 3;
    const int ob = blockIdx.x & 7;
    const int g0 = gb * 4;
    const int o0 = ob * 16;
    const int s0 = ob * 4;
    const int t  = threadIdx.x;
    #pragma unroll
    for (int pass = 0; pass < 40; ++pass) {     // 80 rows x 128 i
        int row = pass * 2 + (t >> 7);
        int i   = t & 127;
        int gg  = row >> 4, ol = row & 15;
        L[gg][ol][i] = P[(size_t)(g0 + gg) * (NO * NI) + (o0 + ol) * NI + i];
    }
    __syncthreads();
    #pragma unroll
    for (int pp = 0; pp < 2; ++pp) {
        int item = pp * 256 + t;                // 4 sl x 128 i
        int i  = item & 127;
        int sl = item >> 7;
        uint32_t* dst = Q2 + ((size_t)((s0 + sl) * NI + i) * NG + g0) * 4;
        #pragma unroll
        for (int gg = 0; gg < 4; ++gg) {
            uint32_t r[4];
            #pragma unroll
            for (int ow = 0; ow < 4; ++ow) {
                float pl = L[gg][sl * 4 + ow][i];
                float dd = L[gg + 1][sl * 4 + ow][i] - pl;
                r[ow] = pack_f16x2(pl, dd);
            }
            *(uint4*)(dst + gg * 4) = make_uint4(r[0], r[1], r[2], r[3]);
        }
    }
}

// ---- K2: bucketize x -> T[i][b] = (idx*16) | (f16(d) << 16) (coalesced) --
__global__ __launch_bounds__(256) void build_t(const float* __restrict__ x,
                                               const float* __restrict__ borders,
                                               const float* __restrict__ icl,
                                               uint32_t* __restrict__ T) {
    const int e0 = (blockIdx.x * 256 + threadIdx.x) * 4;
    const float4 xv = *(const float4*)(x + e0);
    uint32_t r[4];
    const float xs[4] = {xv.x, xv.y, xv.z, xv.w};
    #pragma unroll
    for (int k = 0; k < 4; ++k) {
        float v = xs[k];
        float ea = __expf(-fabsf(v));
        float cdf = v > 0.f ? 1.f - 0.5f * ea : 0.5f * ea;
        int idx = (int)(cdf * 128.f);
        idx = idx > 127 ? 127 : idx;
        float d = (v - borders[idx]) * icl[idx];
        _Float16 hd = (_Float16)d;
        r[k] = ((uint32_t)idx << 4) |
               ((uint32_t)__builtin_bit_cast(unsigned short, hd) << 16);
    }
    *(uint4*)(T + e0) = make_uint4(r[0], r[1], r[2], r[3]);
}

// ---- K3: main. 1024 thr; 64KB persistent slab; 1024 b x 4 o x 32 i -------
// 2 blocks/CU (32 waves). ONE barrier total (post-stage); main loop free-runs.
__global__ __launch_bounds__(1024, 8) void main_k(const uint32_t* __restrict__ Q2,
                                                  const uint32_t* __restrict__ T,
                                                  float* __restrict__ part) {
    __shared__ __align__(16) uint32_t slab[32 * NG * 4];   // 64 KB
    const int t    = threadIdx.x;
    const int bx   = blockIdx.x;
    const int xcd  = bx & 7;                    // == bt (b-tile)
    const int s    = (bx >> 3) & 31;            // o-slice (4 o)
    const int widx = bx >> 8;                   // 0..3
    const int iq   = ((widx << 3) | xcd) >> 3;  // i-quarter = widx
    const int bt   = xcd;                       // b-tile (1024 b)
    const int bme  = (bt << 10) | t;
    const uint32_t* Qs = Q2 + ((size_t)s * NI + iq * 32) * (NG * 4);
    const uint32_t* Tb = T + (size_t)(iq * 32) * NB + bme;

    // one-time stage: 32i x 128g x 4o panel (64 KB; 4 x gll16/thread),
    // T chunk 0 issued under the same drain.
    #pragma unroll
    for (int k = 0; k < 4; ++k)
        load_lds16(Qs + (size_t)(t + k * 1024) * 4, &slab[(t + k * 1024) * 4]);
    uint32_t tt[16];
    #pragma unroll
    for (int il = 0; il < 16; ++il)
        tt[il] = Tb[(size_t)il * NB];
    __syncthreads();                            // ONLY barrier in the kernel

    float a0 = 0.f, a1 = 0.f, a2 = 0.f, a3 = 0.f;
    #pragma unroll
    for (int ic = 0; ic < 2; ++ic) {
        uint32_t tn[16];
        if (ic == 0) {                          // prefetch chunk 1
            #pragma unroll
            for (int il = 0; il < 16; ++il)
                tn[il] = Tb[(size_t)(16 + il) * NB];
        }
        const char* sp = (const char*)slab + ic * 32768;
        #pragma unroll
        for (int il = 0; il < 16; ++il) {
            uint32_t tw  = tt[il];
            uint32_t off = tw & 0xFFFFu;                 // idx*16 bytes
            uint32_t w2b = (tw & 0xFFFF0000u) | 0x3C00u; // {1.0h, d}
            uint4 q = *(const uint4*)(sp + il * 2048 + off);
            half2v w2 = __builtin_bit_cast(half2v, w2b);
            a0 = __builtin_amdgcn_fdot2(__builtin_bit_cast(half2v, q.x), w2, a0, false);
            a1 = __builtin_amdgcn_fdot2(__builtin_bit_cast(half2v, q.y), w2, a1, false);
            a2 = __builtin_amdgcn_fdot2(__builtin_bit_cast(half2v, q.z), w2, a2, false);
            a3 = __builtin_amdgcn_fdot2(__builtin_bit_cast(half2v, q.w), w2, a3, false);
        }
        if (ic == 0) {
            #pragma unroll
            for (int il = 0; il < 16; ++il)
                tt[il] = tn[il];
        }
    }

    // partials part[iq][o][b]: 4KB-contiguous run per o across the block
    float* po = part + (size_t)iq * (NO * NB) + (size_t)(s * 4) * NB + bme;
    po[0]              = a0;
    po[NB]             = a1;
    po[2 * (size_t)NB] = a2;
    po[3 * (size_t)NB] = a3;
}

// ---- K4: out = part0+part1+part2+part3 (1M floats) ----
__global__ __launch_bounds__(256) void reduce_k(const float* __restrict__ part,
                                                float* __restrict__ out) {
    const int e0 = (blockIdx.x * 256 + threadIdx.x) * 4;
    const size_t st = (size_t)NO * NB;
    const float4v v0 = *(const float4v*)(part + e0);
    const float4v v1 = *(const float4v*)(part + st + e0);
    const float4v v2 = *(const float4v*)(part + 2 * st + e0);
    const float4v v3 = *(const float4v*)(part + 3 * st + e0);
    const float4v r  = (v0 + v1) + (v2 + v3);
    __builtin_nontemporal_store(r, (float4v*)(out + e0));
}

extern "C" void kernel_launch(void* const* d_in, const int* in_sizes, int n_in,
                              void* d_out, int out_size, void* d_ws, size_t ws_size,
                              hipStream_t stream) {
    const float* x       = (const float*)d_in[0];
    const float* P       = (const float*)d_in[1];
    const float* borders = (const float*)d_in[2];
    const float* icl     = (const float*)d_in[3];
    float* out = (float*)d_out;

    uint32_t* Q2  = (uint32_t*)d_ws;                 // 8 MB
    uint32_t* T   = Q2 + (size_t)NO * NI * NG;       // 4 MB
    float*    prt = (float*)(T + (size_t)NI * NB);   // 16 MB (four quarters)

    hipLaunchKernelGGL(build_q, dim3(256), dim3(256), 0, stream, P, Q2);
    hipLaunchKernelGGL(build_t, dim3(NI * NB / 1024), dim3(256), 0, stream,
                       x, borders, icl, T);
    hipLaunchKernelGGL(main_k, dim3(1024), dim3(1024), 0, stream, Q2, T, prt);
    hipLaunchKernelGGL(reduce_k, dim3(NO * NB / 1024), dim3(256), 0, stream,
                       prt, out);
}